// Round 1
// baseline (349.615 us; speedup 1.0000x reference)
//
#include <hip/hip_runtime.h>
#include <math.h>

namespace {

constexpr int B  = 16;
constexpr int S  = 1024;
constexpr int H  = 768;
constexpr int NH = 12;
constexpr int DH = 64;
constexpr int FF = 3072;
constexpr int KSPLIT = 8;      // k-splits for xbar accumulation
constexpr float EPS = 1e-12f;

__device__ __forceinline__ float waveReduceSum(float v) {
#pragma unroll
    for (int d = 1; d < 64; d <<= 1) v += __shfl_xor(v, d);
    return v;
}

// block of 768 threads (12 waves); red is __shared__ float[12]
__device__ __forceinline__ float blockReduceSum768(float v, float* red) {
    const int lane = threadIdx.x & 63;
    const int wid  = threadIdx.x >> 6;
    v = waveReduceSum(v);
    __syncthreads();                // protect red across repeated calls
    if (lane == 0) red[wid] = v;
    __syncthreads();
    float s = 0.f;
#pragma unroll
    for (int w = 0; w < 12; ++w) s += red[w];
    return s;
}

// ---------------------------------------------------------------------------
// Generic split-K partial GEMM over the 16 CLS rows:
//   part[sp][b][j] = sum_{i in split sp} A[b,i] * W[i,j]
// A[b,i] = A[b*lda + jt*jtOfsA + i]  (jtOfsA lets ctx use per-head A slices)
// grid (N/64, ISPL), block 256 = 64 j-lanes x 4 b-groups (4 b each)
// ---------------------------------------------------------------------------
template <int K, int ISPL, int N>
__global__ __launch_bounds__(256) void gemm_partial(
        const float* __restrict__ A, int lda, int jtOfsA,
        const float* __restrict__ W, float* __restrict__ part) {
    constexpr int IR = K / ISPL;
    __shared__ float Asl[B * IR];
    const int jt  = blockIdx.x;
    const int sp  = blockIdx.y;
    const int i0  = sp * IR;
    const int tid = threadIdx.x;

    for (int e = tid; e < B * IR; e += 256) {
        const int b = e / IR, ii = e % IR;
        Asl[e] = A[(size_t)b * lda + (size_t)jt * jtOfsA + i0 + ii];
    }
    __syncthreads();

    const int jl = tid & 63;
    const int bg = tid >> 6;                 // 0..3 -> batches bg*4 .. bg*4+3
    const int j  = jt * 64 + jl;
    const float* wp_ = W + (size_t)i0 * N + j;
    const float* a0 = Asl + (bg * 4 + 0) * IR;
    const float* a1 = Asl + (bg * 4 + 1) * IR;
    const float* a2 = Asl + (bg * 4 + 2) * IR;
    const float* a3 = Asl + (bg * 4 + 3) * IR;
    float acc0 = 0.f, acc1 = 0.f, acc2 = 0.f, acc3 = 0.f;
#pragma unroll 4
    for (int ii = 0; ii < IR; ++ii) {
        const float w = wp_[(size_t)ii * N];
        acc0 += w * a0[ii];
        acc1 += w * a1[ii];
        acc2 += w * a2[ii];
        acc3 += w * a3[ii];
    }
    float* pp = part + ((size_t)sp * B) * N + j;
    pp[(size_t)(bg * 4 + 0) * N] = acc0;
    pp[(size_t)(bg * 4 + 1) * N] = acc1;
    pp[(size_t)(bg * 4 + 2) * N] = acc2;
    pp[(size_t)(bg * 4 + 3) * N] = acc3;
}

// out[b,j] = sum_sp part + bias[j]
template <int ISPL, int N>
__global__ __launch_bounds__(256) void reduce_bias(
        const float* __restrict__ part, const float* __restrict__ bias,
        float* __restrict__ out) {
    const int e = blockIdx.x * 256 + threadIdx.x;
    if (e >= B * N) return;
    const int b = e / N, j = e % N;
    float s = bias[j];
#pragma unroll
    for (int sp = 0; sp < ISPL; ++sp) s += part[((size_t)sp * B + b) * N + j];
    out[e] = s;
}

// t[b,f] = gelu_exact(sum_sp part + b1[f])
template <int ISPL, int N>
__global__ __launch_bounds__(256) void reduce_bias_gelu(
        const float* __restrict__ part, const float* __restrict__ bias,
        float* __restrict__ out) {
    const int e = blockIdx.x * 256 + threadIdx.x;
    if (e >= B * N) return;
    const int b = e / N, j = e % N;
    float s = bias[j];
#pragma unroll
    for (int sp = 0; sp < ISPL; ++sp) s += part[((size_t)sp * B + b) * N + j];
    out[e] = 0.5f * s * (1.0f + erff(s * 0.70710678118654752440f));
}

// u[b,h,i] = sum_d wk[i, h*64+d] * q0[b, h*64+d];  constk[b,h] = bk_head . q0_head
__global__ __launch_bounds__(256) void u_kernel(
        const float* __restrict__ q0, const float* __restrict__ wk,
        const float* __restrict__ bk, float* __restrict__ u,
        float* __restrict__ constk) {
    const int b = blockIdx.x / NH, h = blockIdx.x % NH;
    __shared__ float qh[DH];
    const int tid = threadIdx.x;
    if (tid < DH) qh[tid] = q0[b * H + h * DH + tid];
    __syncthreads();
    if (tid < DH) {     // wave 0 computes constk
        float v = bk[h * DH + tid] * qh[tid];
        v = waveReduceSum(v);
        if (tid == 0) constk[b * NH + h] = v;
    }
    for (int i = tid; i < H; i += 256) {
        const float4* wr4 = (const float4*)(wk + (size_t)i * H + h * DH);
        float s = 0.f;
#pragma unroll
        for (int d4 = 0; d4 < DH / 4; ++d4) {
            const float4 w = wr4[d4];
            s += w.x * qh[4 * d4 + 0] + w.y * qh[4 * d4 + 1]
               + w.z * qh[4 * d4 + 2] + w.w * qh[4 * d4 + 3];
        }
        u[((size_t)(b * NH + h)) * H + i] = s;
    }
}

// scores[b,h,k] = (x[b,k,:] . u[b,h,:] + constk[b,h]) / 8 + mask[b,k]
// grid (B, S/64), block 256 (4 waves); each wave handles 16 k's, all 12 heads
__global__ __launch_bounds__(256) void score_kernel(
        const float* __restrict__ x, const float* __restrict__ u,
        const float* __restrict__ constk, const float* __restrict__ mask,
        float* __restrict__ scores) {
    const int b  = blockIdx.x;
    const int kt = blockIdx.y;
    __shared__ __align__(16) float ul[NH * H];
    __shared__ float ck[NH];
    const int tid = threadIdx.x;
    for (int e = tid; e < NH * H; e += 256) ul[e] = u[(size_t)b * NH * H + e];
    if (tid < NH) ck[tid] = constk[b * NH + tid];
    __syncthreads();

    const int wid = tid >> 6, lane = tid & 63;
    for (int kk = wid; kk < 64; kk += 4) {
        const int k = kt * 64 + kk;
        const float* xr = x + (size_t)b * S * H + (size_t)k * H;
        const float4 x0 = *(const float4*)(xr + lane * 4);
        const float4 x1 = *(const float4*)(xr + 256 + lane * 4);
        const float4 x2 = *(const float4*)(xr + 512 + lane * 4);
        const float mk = mask[b * S + k];
#pragma unroll
        for (int h = 0; h < NH; ++h) {
            const float* ur = ul + h * H;
            const float4 u0 = *(const float4*)(ur + lane * 4);
            const float4 u1 = *(const float4*)(ur + 256 + lane * 4);
            const float4 u2 = *(const float4*)(ur + 512 + lane * 4);
            float s = x0.x * u0.x + x0.y * u0.y + x0.z * u0.z + x0.w * u0.w
                    + x1.x * u1.x + x1.y * u1.y + x1.z * u1.z + x1.w * u1.w
                    + x2.x * u2.x + x2.y * u2.y + x2.z * u2.z + x2.w * u2.w;
            s = waveReduceSum(s);
            if (lane == 0)
                scores[((size_t)(b * NH + h)) * S + k] = s * 0.125f + ck[h] + mk;
        }
    }
}

// in-place softmax over S=1024 per (b,h) row
__global__ __launch_bounds__(256) void softmax_kernel(float* __restrict__ scores) {
    float* p = scores + (size_t)blockIdx.x * S;
    const int tid = threadIdx.x, wid = tid >> 6, lane = tid & 63;
    float4 v = *(float4*)(p + tid * 4);
    __shared__ float redm[4], reds[4];
    float m = fmaxf(fmaxf(v.x, v.y), fmaxf(v.z, v.w));
#pragma unroll
    for (int d = 1; d < 64; d <<= 1) m = fmaxf(m, __shfl_xor(m, d));
    if (lane == 0) redm[wid] = m;
    __syncthreads();
    m = fmaxf(fmaxf(redm[0], redm[1]), fmaxf(redm[2], redm[3]));
    v.x = expf(v.x - m); v.y = expf(v.y - m);
    v.z = expf(v.z - m); v.w = expf(v.w - m);
    float s = v.x + v.y + v.z + v.w;
    s = waveReduceSum(s);
    if (lane == 0) reds[wid] = s;
    __syncthreads();
    s = reds[0] + reds[1] + reds[2] + reds[3];
    const float inv = 1.0f / s;
    v.x *= inv; v.y *= inv; v.z *= inv; v.w *= inv;
    *(float4*)(p + tid * 4) = v;
}

// xpart[b,sp,h,j] = sum_{k in split} probs[b,h,k] * x[b,k,j]
// grid (B, KSPLIT), block 768
__global__ __launch_bounds__(768) void xbar_partial(
        const float* __restrict__ x, const float* __restrict__ probs,
        float* __restrict__ xpart) {
    constexpr int KR = S / KSPLIT;   // 128
    const int b = blockIdx.x, sp = blockIdx.y;
    __shared__ float pl[NH * KR];
    const int tid = threadIdx.x;
    for (int e = tid; e < NH * KR; e += 768) {
        const int h = e / KR, kk = e % KR;
        pl[e] = probs[((size_t)(b * NH + h)) * S + sp * KR + kk];
    }
    __syncthreads();
    float acc[NH];
#pragma unroll
    for (int h = 0; h < NH; ++h) acc[h] = 0.f;
    const float* xr = x + (size_t)b * S * H + (size_t)sp * KR * H + tid;
    for (int kk = 0; kk < KR; ++kk) {
        const float xv = xr[(size_t)kk * H];
#pragma unroll
        for (int h = 0; h < NH; ++h) acc[h] += pl[h * KR + kk] * xv;
    }
#pragma unroll
    for (int h = 0; h < NH; ++h)
        xpart[(((size_t)b * KSPLIT + sp) * NH + h) * H + tid] = acc[h];
}

__global__ __launch_bounds__(256) void xbar_reduce(
        const float* __restrict__ xpart, float* __restrict__ xbar) {
    const int e = blockIdx.x * 256 + threadIdx.x;
    if (e >= B * NH * H) return;
    const int b = e / (NH * H), rem = e % (NH * H);
    float s = 0.f;
#pragma unroll
    for (int sp = 0; sp < KSPLIT; ++sp)
        s += xpart[((size_t)b * KSPLIT + sp) * NH * H + rem];
    xbar[e] = s;
}

// out[b,:] = LayerNorm( sum_sp part + bias + resid[b*stride + :] ) * g + beta
template <int ISPL>
__global__ __launch_bounds__(768) void ln_kernel(
        const float* __restrict__ part, const float* __restrict__ bias,
        const float* __restrict__ resid, int residStride,
        const float* __restrict__ g, const float* __restrict__ bet,
        float* __restrict__ out) {
    __shared__ float red[12];
    const int b = blockIdx.x, j = threadIdx.x;
    float v = bias[j] + resid[(size_t)b * residStride + j];
#pragma unroll
    for (int sp = 0; sp < ISPL; ++sp) v += part[((size_t)sp * B + b) * H + j];
    const float mu = blockReduceSum768(v, red) * (1.0f / H);
    const float d  = v - mu;
    const float var = blockReduceSum768(d * d, red) * (1.0f / H);
    out[(size_t)b * H + j] = d * rsqrtf(var + EPS) * g[j] + bet[j];
}

// pooled = tanh(sum_sp part + bp); cls[b] = pooled . wm + bm
__global__ __launch_bounds__(768) void cls_kernel(
        const float* __restrict__ part, const float* __restrict__ bp,
        const float* __restrict__ wm, const float* __restrict__ bm,
        float* __restrict__ out) {
    __shared__ float red[12];
    const int b = blockIdx.x, j = threadIdx.x;
    float v = bp[j];
#pragma unroll
    for (int sp = 0; sp < 6; ++sp) v += part[((size_t)sp * B + b) * H + j];
    v = tanhf(v);
    const float s = blockReduceSum768(v * wm[j], red);
    if (j == 0) out[b] = s + bm[0];
}

} // namespace

extern "C" void kernel_launch(void* const* d_in, const int* in_sizes, int n_in,
                              void* d_out, int out_size, void* d_ws, size_t ws_size,
                              hipStream_t stream) {
    const float* x    = (const float*)d_in[0];
    const float* mask = (const float*)d_in[1];
    const float* wq   = (const float*)d_in[2];
    const float* bq   = (const float*)d_in[3];
    const float* wk   = (const float*)d_in[4];
    const float* bk   = (const float*)d_in[5];
    const float* wv   = (const float*)d_in[6];
    const float* bv   = (const float*)d_in[7];
    const float* wo   = (const float*)d_in[8];
    const float* bo   = (const float*)d_in[9];
    const float* ln1g = (const float*)d_in[10];
    const float* ln1b = (const float*)d_in[11];
    const float* w1   = (const float*)d_in[12];
    const float* b1   = (const float*)d_in[13];
    const float* w2   = (const float*)d_in[14];
    const float* b2   = (const float*)d_in[15];
    const float* ln2g = (const float*)d_in[16];
    const float* ln2b = (const float*)d_in[17];
    const float* wp   = (const float*)d_in[18];
    const float* bp   = (const float*)d_in[19];
    const float* wm   = (const float*)d_in[20];
    const float* bm   = (const float*)d_in[21];
    float* out = (float*)d_out;

    float* ws = (float*)d_ws;
    size_t o = 0;
    float* q0_part   = ws + o; o += (size_t)6 * B * H;         // 73728
    float* q0        = ws + o; o += (size_t)B * H;             // 12288
    float* u         = ws + o; o += (size_t)B * NH * H;        // 147456
    float* constk    = ws + o; o += (size_t)B * NH;            // 192
    float* scores    = ws + o; o += (size_t)B * NH * S;        // 196608
    float* xpart     = ws + o; o += (size_t)B * KSPLIT * NH * H; // 1179648
    float* xbar      = ws + o; o += (size_t)B * NH * H;        // 147456
    float* ctx_part  = ws + o; o += (size_t)6 * B * H;
    float* ctx       = ws + o; o += (size_t)B * H;
    float* attn_part = ws + o; o += (size_t)6 * B * H;
    float* attn_out  = ws + o; o += (size_t)B * H;
    float* ffn1_part = ws + o; o += (size_t)6 * B * FF;        // 294912
    float* tbuf      = ws + o; o += (size_t)B * FF;            // 49152
    float* ffn2_part = ws + o; o += (size_t)24 * B * H;        // 294912
    float* hidden    = ws + o; o += (size_t)B * H;
    float* pool_part = ws + o; o += (size_t)6 * B * H;
    (void)ws_size; (void)in_sizes; (void)n_in; (void)out_size;

    // 1) q0 = x[:,0,:] @ wq + bq
    gemm_partial<H, 6, H><<<dim3(12, 6), 256, 0, stream>>>(x, S * H, 0, wq, q0_part);
    reduce_bias<6, H><<<48, 256, 0, stream>>>(q0_part, bq, q0);

    // 2) u[b,h,:] = wk_head @ q0_head ; constk = bk_head . q0_head
    u_kernel<<<B * NH, 256, 0, stream>>>(q0, wk, bk, u, constk);

    // 3) scores + mask (reads x once)
    score_kernel<<<dim3(B, S / 64), 256, 0, stream>>>(x, u, constk, mask, scores);

    // 4) softmax in place
    softmax_kernel<<<B * NH, 256, 0, stream>>>(scores);

    // 5) xbar[b,h,:] = sum_k p * x[b,k,:]  (reads x once more)
    xbar_partial<<<dim3(B, KSPLIT), 768, 0, stream>>>(x, scores, xpart);
    xbar_reduce<<<(B * NH * H + 255) / 256, 256, 0, stream>>>(xpart, xbar);

    // 6) ctx[b, h*64+d] = xbar[b,h,:] . wv[:, h*64+d] + bv   (jtOfsA=H: head per j-tile)
    gemm_partial<H, 6, H><<<dim3(12, 6), 256, 0, stream>>>(xbar, NH * H, H, wv, ctx_part);
    reduce_bias<6, H><<<48, 256, 0, stream>>>(ctx_part, bv, ctx);

    // 7) attn_out = LN1(ctx @ wo + bo + x[:,0,:])
    gemm_partial<H, 6, H><<<dim3(12, 6), 256, 0, stream>>>(ctx, H, 0, wo, attn_part);
    ln_kernel<6><<<B, 768, 0, stream>>>(attn_part, bo, x, S * H, ln1g, ln1b, attn_out);

    // 8) FFN: t = gelu(attn_out @ w1 + b1); ffn = t @ w2 + b2; hidden = LN2(ffn + attn_out)
    gemm_partial<H, 6, FF><<<dim3(48, 6), 256, 0, stream>>>(attn_out, H, 0, w1, ffn1_part);
    reduce_bias_gelu<6, FF><<<192, 256, 0, stream>>>(ffn1_part, b1, tbuf);
    gemm_partial<FF, 24, H><<<dim3(12, 24), 256, 0, stream>>>(tbuf, FF, 0, w2, ffn2_part);
    ln_kernel<24><<<B, 768, 0, stream>>>(ffn2_part, b2, attn_out, H, ln2g, ln2b, hidden);

    // 9) pooled = tanh(hidden @ wp + bp); cls = pooled @ wm + bm
    gemm_partial<H, 6, H><<<dim3(12, 6), 256, 0, stream>>>(hidden, H, 0, wp, pool_part);
    cls_kernel<<<B, 768, 0, stream>>>(pool_part, bp, wm, bm, out);
}

// Round 2
// 235.557 us; speedup vs baseline: 1.4842x; 1.4842x over previous
//
#include <hip/hip_runtime.h>
#include <math.h>

namespace {

constexpr int B  = 16;
constexpr int S  = 1024;
constexpr int H  = 768;
constexpr int NH = 12;
constexpr int DH = 64;
constexpr int FF = 3072;
constexpr int KSPL = 8;        // k-splits for xbar accumulation
constexpr float EPS = 1e-12f;

__device__ __forceinline__ float waveReduceSum(float v) {
#pragma unroll
    for (int d = 1; d < 64; d <<= 1) v += __shfl_xor(v, d);
    return v;
}

__device__ __forceinline__ float blockReduceSum768(float v, float* red) {
    const int lane = threadIdx.x & 63;
    const int wid  = threadIdx.x >> 6;
    v = waveReduceSum(v);
    __syncthreads();
    if (lane == 0) red[wid] = v;
    __syncthreads();
    float s = 0.f;
#pragma unroll
    for (int w = 0; w < 12; ++w) s += red[w];
    return s;
}

// ---------------------------------------------------------------------------
// split-K partial GEMM over the 16 CLS rows:
//   part[sp][b][j] = sum_{i in split sp} A[b,i] * W[i,j]
// grid (N/64, ISPL), block 256 = 64 j-lanes x 4 b-groups
// ---------------------------------------------------------------------------
template <int K, int ISPL, int N>
__global__ __launch_bounds__(256) void gemm_partial(
        const float* __restrict__ A, int lda, int jtOfsA,
        const float* __restrict__ W, float* __restrict__ part) {
    constexpr int IR = K / ISPL;
    __shared__ float Asl[B * IR];
    const int jt  = blockIdx.x;
    const int sp  = blockIdx.y;
    const int i0  = sp * IR;
    const int tid = threadIdx.x;

    for (int e = tid; e < B * IR; e += 256) {
        const int b = e / IR, ii = e % IR;
        Asl[e] = A[(size_t)b * lda + (size_t)jt * jtOfsA + i0 + ii];
    }
    __syncthreads();

    const int jl = tid & 63;
    const int bg = tid >> 6;
    const int j  = jt * 64 + jl;
    const float* wp_ = W + (size_t)i0 * N + j;
    const float* a0 = Asl + (bg * 4 + 0) * IR;
    const float* a1 = Asl + (bg * 4 + 1) * IR;
    const float* a2 = Asl + (bg * 4 + 2) * IR;
    const float* a3 = Asl + (bg * 4 + 3) * IR;
    float acc0 = 0.f, acc1 = 0.f, acc2 = 0.f, acc3 = 0.f;
#pragma unroll 8
    for (int ii = 0; ii < IR; ++ii) {
        const float w = wp_[(size_t)ii * N];
        acc0 += w * a0[ii];
        acc1 += w * a1[ii];
        acc2 += w * a2[ii];
        acc3 += w * a3[ii];
    }
    float* pp = part + ((size_t)sp * B) * N + j;
    pp[(size_t)(bg * 4 + 0) * N] = acc0;
    pp[(size_t)(bg * 4 + 1) * N] = acc1;
    pp[(size_t)(bg * 4 + 2) * N] = acc2;
    pp[(size_t)(bg * 4 + 3) * N] = acc3;
}

// Same, but A is itself a split-K partial set: A[b,i] = bias[i] + sum_sp2 Ain[sp2][b][i]
template <int K, int ISPL, int N, int RED>
__global__ __launch_bounds__(256) void gemm_partial_red(
        const float* __restrict__ Ain, const float* __restrict__ bias,
        const float* __restrict__ W, float* __restrict__ part) {
    constexpr int IR = K / ISPL;
    __shared__ float Asl[B * IR];
    const int jt  = blockIdx.x;
    const int sp  = blockIdx.y;
    const int i0  = sp * IR;
    const int tid = threadIdx.x;

    for (int e = tid; e < B * IR; e += 256) {
        const int b = e / IR, ii = e % IR;
        float v = bias[i0 + ii];
#pragma unroll
        for (int sp2 = 0; sp2 < RED; ++sp2)
            v += Ain[((size_t)sp2 * B + b) * K + i0 + ii];
        Asl[e] = v;
    }
    __syncthreads();

    const int jl = tid & 63;
    const int bg = tid >> 6;
    const int j  = jt * 64 + jl;
    const float* wp_ = W + (size_t)i0 * N + j;
    const float* a0 = Asl + (bg * 4 + 0) * IR;
    const float* a1 = Asl + (bg * 4 + 1) * IR;
    const float* a2 = Asl + (bg * 4 + 2) * IR;
    const float* a3 = Asl + (bg * 4 + 3) * IR;
    float acc0 = 0.f, acc1 = 0.f, acc2 = 0.f, acc3 = 0.f;
#pragma unroll 8
    for (int ii = 0; ii < IR; ++ii) {
        const float w = wp_[(size_t)ii * N];
        acc0 += w * a0[ii];
        acc1 += w * a1[ii];
        acc2 += w * a2[ii];
        acc3 += w * a3[ii];
    }
    float* pp = part + ((size_t)sp * B) * N + j;
    pp[(size_t)(bg * 4 + 0) * N] = acc0;
    pp[(size_t)(bg * 4 + 1) * N] = acc1;
    pp[(size_t)(bg * 4 + 2) * N] = acc2;
    pp[(size_t)(bg * 4 + 3) * N] = acc3;
}

// t[b,f] = gelu_exact(sum_sp part + b1[f])
template <int ISPL, int N>
__global__ __launch_bounds__(256) void reduce_bias_gelu(
        const float* __restrict__ part, const float* __restrict__ bias,
        float* __restrict__ out) {
    const int e = blockIdx.x * 256 + threadIdx.x;
    if (e >= B * N) return;
    const int b = e / N, j = e % N;
    float s = bias[j];
#pragma unroll
    for (int sp = 0; sp < ISPL; ++sp) s += part[((size_t)sp * B + b) * N + j];
    out[e] = 0.5f * s * (1.0f + erff(s * 0.70710678118654752440f));
}

// u[b,h,i] = sum_d wk[i, h*64+d] * (q0 reduced); constk[b,h] = bk_h . q0_h
// grid (B*NH), block 256 = 64 i x 4 jj
__global__ __launch_bounds__(256) void u_kernel(
        const float* __restrict__ q0_part, const float* __restrict__ bq,
        const float* __restrict__ wk, const float* __restrict__ bk,
        float* __restrict__ u, float* __restrict__ constk) {
    const int b = blockIdx.x / NH, h = blockIdx.x % NH;
    __shared__ float qh[DH];
    const int tid = threadIdx.x;
    if (tid < DH) {
        float v = bq[h * DH + tid];
#pragma unroll
        for (int sp = 0; sp < 24; ++sp)
            v += q0_part[((size_t)sp * B + b) * H + h * DH + tid];
        qh[tid] = v;
    }
    __syncthreads();
    if (tid < DH) {
        float v = bk[h * DH + tid] * qh[tid];
        v = waveReduceSum(v);
        if (tid == 0) constk[b * NH + h] = v;
    }
    const int jj = tid & 3, iq = tid >> 2;   // jj: 16-float chunk of the 64-d head
    const float4* qv = (const float4*)qh;
    float4 q4[4];
#pragma unroll
    for (int c = 0; c < 4; ++c) q4[c] = qv[jj * 4 + c];
#pragma unroll
    for (int ir = 0; ir < 12; ++ir) {
        const int i = ir * 64 + iq;
        const float4* wr = (const float4*)(wk + (size_t)i * H + h * DH);
        float s = 0.f;
#pragma unroll
        for (int c = 0; c < 4; ++c) {
            const float4 w = wr[jj * 4 + c];
            s += w.x * q4[c].x + w.y * q4[c].y + w.z * q4[c].z + w.w * q4[c].w;
        }
        s += __shfl_xor(s, 1);
        s += __shfl_xor(s, 2);
        if (jj == 0) u[((size_t)(b * NH + h)) * H + i] = s;
    }
}

// scores[b,h,k] = (x[b,k,:] . u[b,h,:] + constk[b,h]) / 8 + mask[b,k]
// grid (B, S/32), block 256: kk=tid>>4 owns 2 k-rows, jj=tid&15 owns an
// interleaved 48-float j-slice (float4 id jj+16t). 16-lane shfl reduce.
__global__ __launch_bounds__(256, 2) void score_kernel(
        const float* __restrict__ x, const float* __restrict__ u,
        const float* __restrict__ constk, const float* __restrict__ mask,
        float* __restrict__ scores) {
    const int b  = blockIdx.x;
    const int kt = blockIdx.y;
    __shared__ __align__(16) float ul[NH * H];
    __shared__ float ck[NH];
    const int tid = threadIdx.x;
    {
        const float4* ug = (const float4*)(u + (size_t)b * NH * H);
        float4* ul4 = (float4*)ul;
        for (int e = tid; e < NH * H / 4; e += 256) ul4[e] = ug[e];
        if (tid < NH) ck[tid] = constk[b * NH + tid];
    }
    __syncthreads();

    const int jj = tid & 15, kk = tid >> 4;
    const int k0 = kt * 32 + kk * 2;
    float4 xv0[12], xv1[12];
    {
        const float4* xr0 = (const float4*)(x + ((size_t)b * S + k0) * H);
        const float4* xr1 = (const float4*)(x + ((size_t)b * S + k0 + 1) * H);
#pragma unroll
        for (int t = 0; t < 12; ++t) { xv0[t] = xr0[jj + 16 * t]; xv1[t] = xr1[jj + 16 * t]; }
    }
    const float4* ul4 = (const float4*)ul;
    float acc0[NH], acc1[NH];
#pragma unroll
    for (int h = 0; h < NH; ++h) {
        float a0 = 0.f, a1 = 0.f;
#pragma unroll
        for (int t = 0; t < 12; ++t) {
            const float4 uv = ul4[h * 192 + jj + 16 * t];
            a0 += xv0[t].x * uv.x + xv0[t].y * uv.y + xv0[t].z * uv.z + xv0[t].w * uv.w;
            a1 += xv1[t].x * uv.x + xv1[t].y * uv.y + xv1[t].z * uv.z + xv1[t].w * uv.w;
        }
        acc0[h] = a0; acc1[h] = a1;
    }
#pragma unroll
    for (int h = 0; h < NH; ++h) {
#pragma unroll
        for (int d = 1; d < 16; d <<= 1) {
            acc0[h] += __shfl_xor(acc0[h], d);
            acc1[h] += __shfl_xor(acc1[h], d);
        }
    }
    if (jj == 0) {
        const float mk0 = mask[b * S + k0];
        const float mk1 = mask[b * S + k0 + 1];
#pragma unroll
        for (int h = 0; h < NH; ++h) {
            scores[((size_t)(b * NH + h)) * S + k0]     = acc0[h] * 0.125f + ck[h] + mk0;
            scores[((size_t)(b * NH + h)) * S + k0 + 1] = acc1[h] * 0.125f + ck[h] + mk1;
        }
    }
}

// softmax over S per (b,h); writes TRANSPOSED p_t[b][k][h]
__global__ __launch_bounds__(256) void softmax_kernel(
        const float* __restrict__ scores, float* __restrict__ p_t) {
    const int bh = blockIdx.x;
    const int b = bh / NH, h = bh % NH;
    const float* p = scores + (size_t)bh * S;
    const int tid = threadIdx.x, wid = tid >> 6, lane = tid & 63;
    float4 v = *(const float4*)(p + tid * 4);
    __shared__ float redm[4], reds[4];
    float m = fmaxf(fmaxf(v.x, v.y), fmaxf(v.z, v.w));
#pragma unroll
    for (int d = 1; d < 64; d <<= 1) m = fmaxf(m, __shfl_xor(m, d));
    if (lane == 0) redm[wid] = m;
    __syncthreads();
    m = fmaxf(fmaxf(redm[0], redm[1]), fmaxf(redm[2], redm[3]));
    v.x = expf(v.x - m); v.y = expf(v.y - m);
    v.z = expf(v.z - m); v.w = expf(v.w - m);
    float s = v.x + v.y + v.z + v.w;
    s = waveReduceSum(s);
    if (lane == 0) reds[wid] = s;
    __syncthreads();
    s = reds[0] + reds[1] + reds[2] + reds[3];
    const float inv = 1.0f / s;
    float* pt = p_t + ((size_t)b * S + tid * 4) * NH + h;
    pt[0 * NH] = v.x * inv;
    pt[1 * NH] = v.y * inv;
    pt[2 * NH] = v.z * inv;
    pt[3 * NH] = v.w * inv;
}

// xpart[b,sp,h,j] = sum_{k in split} p_t[b,k,h] * x[b,k,j]
// grid (B, KSPL), block 768; p reads are wave-uniform -> scalar loads
__global__ __launch_bounds__(768) void xbar_partial(
        const float* __restrict__ x, const float* __restrict__ p_t,
        float* __restrict__ xpart) {
    constexpr int KR = S / KSPL;   // 128
    const int b = blockIdx.x, sp = blockIdx.y;
    const int tid = threadIdx.x;
    float acc[NH];
#pragma unroll
    for (int h = 0; h < NH; ++h) acc[h] = 0.f;
    const float* xr = x + ((size_t)b * S + sp * KR) * H + tid;
    const float* pr = p_t + ((size_t)b * S + sp * KR) * NH;
#pragma unroll 4
    for (int kk = 0; kk < KR; ++kk) {
        const float xv = xr[(size_t)kk * H];
#pragma unroll
        for (int h = 0; h < NH; ++h) acc[h] += pr[kk * NH + h] * xv;
    }
    float* op = xpart + ((size_t)(b * KSPL + sp)) * NH * H + tid;
#pragma unroll
    for (int h = 0; h < NH; ++h) op[(size_t)h * H] = acc[h];
}

__global__ __launch_bounds__(256) void xbar_reduce(
        const float* __restrict__ xpart, float* __restrict__ xbar) {
    const int e = blockIdx.x * 256 + threadIdx.x;
    if (e >= B * NH * H) return;
    const int b = e / (NH * H), rem = e % (NH * H);
    float s = 0.f;
#pragma unroll
    for (int sp = 0; sp < KSPL; ++sp)
        s += xpart[((size_t)(b * KSPL + sp)) * NH * H + rem];
    xbar[e] = s;
}

// out[b,:] = LayerNorm( sum_sp part + bias + resid ) * g + beta
template <int ISPL>
__global__ __launch_bounds__(768) void ln_kernel(
        const float* __restrict__ part, const float* __restrict__ bias,
        const float* __restrict__ resid, int residStride,
        const float* __restrict__ g, const float* __restrict__ bet,
        float* __restrict__ out) {
    __shared__ float red[12];
    const int b = blockIdx.x, j = threadIdx.x;
    float v = bias[j] + resid[(size_t)b * residStride + j];
#pragma unroll
    for (int sp = 0; sp < ISPL; ++sp) v += part[((size_t)sp * B + b) * H + j];
    const float mu = blockReduceSum768(v, red) * (1.0f / H);
    const float d  = v - mu;
    const float var = blockReduceSum768(d * d, red) * (1.0f / H);
    out[(size_t)b * H + j] = d * rsqrtf(var + EPS) * g[j] + bet[j];
}

// pooled = tanh(sum_sp part + bp); cls[b] = pooled . wm + bm
template <int ISPL>
__global__ __launch_bounds__(768) void cls_kernel(
        const float* __restrict__ part, const float* __restrict__ bp,
        const float* __restrict__ wm, const float* __restrict__ bm,
        float* __restrict__ out) {
    __shared__ float red[12];
    const int b = blockIdx.x, j = threadIdx.x;
    float v = bp[j];
#pragma unroll
    for (int sp = 0; sp < ISPL; ++sp) v += part[((size_t)sp * B + b) * H + j];
    v = tanhf(v);
    const float s = blockReduceSum768(v * wm[j], red);
    if (j == 0) out[b] = s + bm[0];
}

} // namespace

extern "C" void kernel_launch(void* const* d_in, const int* in_sizes, int n_in,
                              void* d_out, int out_size, void* d_ws, size_t ws_size,
                              hipStream_t stream) {
    const float* x    = (const float*)d_in[0];
    const float* mask = (const float*)d_in[1];
    const float* wq   = (const float*)d_in[2];
    const float* bq   = (const float*)d_in[3];
    const float* wk   = (const float*)d_in[4];
    const float* bk   = (const float*)d_in[5];
    const float* wv   = (const float*)d_in[6];
    const float* bv   = (const float*)d_in[7];
    const float* wo   = (const float*)d_in[8];
    const float* bo   = (const float*)d_in[9];
    const float* ln1g = (const float*)d_in[10];
    const float* ln1b = (const float*)d_in[11];
    const float* w1   = (const float*)d_in[12];
    const float* b1   = (const float*)d_in[13];
    const float* w2   = (const float*)d_in[14];
    const float* b2   = (const float*)d_in[15];
    const float* ln2g = (const float*)d_in[16];
    const float* ln2b = (const float*)d_in[17];
    const float* wp   = (const float*)d_in[18];
    const float* bp   = (const float*)d_in[19];
    const float* wm   = (const float*)d_in[20];
    const float* bm   = (const float*)d_in[21];
    float* out = (float*)d_out;

    // -------- workspace arena (lifetime-overlapped; ~7.0 MB total) --------
    float* ws = (float*)d_ws;
    size_t o = 0;
    float* u        = ws + o; o += (size_t)B * NH * H;      // 147456
    float* constk   = ws + o; o += 256;
    float* p_t      = ws + o; o += (size_t)B * S * NH;      // 196608
    float* xbar     = ws + o; o += (size_t)B * NH * H;      // 147456
    float* attn_out = ws + o; o += (size_t)B * H;
    float* tbuf     = ws + o; o += (size_t)B * FF;          // 49152
    float* hidden   = ws + o; o += (size_t)B * H;
    float* arena    = ws + o;                                // 1179648 floats
    // arena aliases (sequential lifetimes):
    float* q0_part   = arena;                 // 24*B*H   = 294912
    float* scores    = arena;                 // B*NH*S   = 196608 (after u_kernel)
    float* xpart     = arena;                 // KSPL*B*NH*H = 1179648 (after softmax)
    float* ctx_part  = arena;                 // 24*B*H (after xbar_reduce)
    float* wo_part   = arena + (size_t)24 * B * H;  // 294912 (ctx_part still live)
    float* ffn1_part = arena;                 // 24*B*FF = 1179648 (after ln1)
    float* ffn2_part = arena;                 // 48*B*H = 589824 (after gelu reduce)
    float* pool_part = arena;                 // 24*B*H (after ln2)
    (void)ws_size; (void)in_sizes; (void)n_in; (void)out_size;

    // 1) q0 partials = x[:,0,:] @ wq
    gemm_partial<H, 24, H><<<dim3(12, 24), 256, 0, stream>>>(x, S * H, 0, wq, q0_part);

    // 2) u[b,h,:] = wk_head @ q0_head (fuses q0 reduce + bq); constk = bk_h . q0_h
    u_kernel<<<B * NH, 256, 0, stream>>>(q0_part, bq, wk, bk, u, constk);

    // 3) scores (reads x once)
    score_kernel<<<dim3(B, S / 32), 256, 0, stream>>>(x, u, constk, mask, scores);

    // 4) softmax -> transposed p_t[b][k][h]
    softmax_kernel<<<B * NH, 256, 0, stream>>>(scores, p_t);

    // 5) xbar[b,h,:] = sum_k p x[b,k,:]  (reads x once more)
    xbar_partial<<<dim3(B, KSPL), 768, 0, stream>>>(x, p_t, xpart);
    xbar_reduce<<<(B * NH * H + 255) / 256, 256, 0, stream>>>(xpart, xbar);

    // 6) ctx partials: per-head xbar slice @ wv
    gemm_partial<H, 24, H><<<dim3(12, 24), 256, 0, stream>>>(xbar, NH * H, H, wv, ctx_part);

    // 7) wo GEMM with fused ctx reduce+bv in staging; then LN1 with residual x[:,0,:]
    gemm_partial_red<H, 24, H, 24><<<dim3(12, 24), 256, 0, stream>>>(ctx_part, bv, wo, wo_part);
    ln_kernel<24><<<B, 768, 0, stream>>>(wo_part, bo, x, S * H, ln1g, ln1b, attn_out);

    // 8) FFN
    gemm_partial<H, 24, FF><<<dim3(48, 24), 256, 0, stream>>>(attn_out, H, 0, w1, ffn1_part);
    reduce_bias_gelu<24, FF><<<192, 256, 0, stream>>>(ffn1_part, b1, tbuf);
    gemm_partial<FF, 48, H><<<dim3(12, 48), 256, 0, stream>>>(tbuf, FF, 0, w2, ffn2_part);
    ln_kernel<48><<<B, 768, 0, stream>>>(ffn2_part, b2, attn_out, H, ln2g, ln2b, hidden);

    // 9) pooler + classifier
    gemm_partial<H, 24, H><<<dim3(12, 24), 256, 0, stream>>>(hidden, H, 0, wp, pool_part);
    cls_kernel<24><<<B, 768, 0, stream>>>(pool_part, bp, wm, bm, out);
}

// Round 3
// 210.559 us; speedup vs baseline: 1.6604x; 1.1187x over previous
//
#include <hip/hip_runtime.h>
#include <math.h>

namespace {

constexpr int B  = 16;
constexpr int S  = 1024;
constexpr int H  = 768;
constexpr int NH = 12;
constexpr int DH = 64;
constexpr int FF = 3072;
constexpr int KSPL = 16;       // k-splits for xbar accumulation
constexpr float EPS = 1e-12f;

__device__ __forceinline__ float waveReduceSum(float v) {
#pragma unroll
    for (int d = 1; d < 64; d <<= 1) v += __shfl_xor(v, d);
    return v;
}

__device__ __forceinline__ float blockReduceSum768(float v, float* red) {
    const int lane = threadIdx.x & 63;
    const int wid  = threadIdx.x >> 6;
    v = waveReduceSum(v);
    __syncthreads();
    if (lane == 0) red[wid] = v;
    __syncthreads();
    float s = 0.f;
#pragma unroll
    for (int w = 0; w < 12; ++w) s += red[w];
    return s;
}

// ---------------------------------------------------------------------------
// split-K partial GEMM over the 16 CLS rows:
//   part[sp][b][j] = sum_{i in split sp} A[b,i] * W[i,j]
// grid (N/64, ISPL), block 256 = 64 j-lanes x 4 b-groups
// ---------------------------------------------------------------------------
template <int K, int ISPL, int N>
__global__ __launch_bounds__(256) void gemm_partial(
        const float* __restrict__ A, int lda, int jtOfsA,
        const float* __restrict__ W, float* __restrict__ part) {
    constexpr int IR = K / ISPL;
    __shared__ float Asl[B * IR];
    const int jt  = blockIdx.x;
    const int sp  = blockIdx.y;
    const int i0  = sp * IR;
    const int tid = threadIdx.x;

    for (int e = tid; e < B * IR; e += 256) {
        const int b = e / IR, ii = e % IR;
        Asl[e] = A[(size_t)b * lda + (size_t)jt * jtOfsA + i0 + ii];
    }
    __syncthreads();

    const int jl = tid & 63;
    const int bg = tid >> 6;
    const int j  = jt * 64 + jl;
    const float* wp_ = W + (size_t)i0 * N + j;
    const float* a0 = Asl + (bg * 4 + 0) * IR;
    const float* a1 = Asl + (bg * 4 + 1) * IR;
    const float* a2 = Asl + (bg * 4 + 2) * IR;
    const float* a3 = Asl + (bg * 4 + 3) * IR;
    float acc0 = 0.f, acc1 = 0.f, acc2 = 0.f, acc3 = 0.f;
#pragma unroll
    for (int ii = 0; ii < IR; ++ii) {
        const float w = wp_[(size_t)ii * N];
        acc0 += w * a0[ii];
        acc1 += w * a1[ii];
        acc2 += w * a2[ii];
        acc3 += w * a3[ii];
    }
    float* pp = part + ((size_t)sp * B) * N + j;
    pp[(size_t)(bg * 4 + 0) * N] = acc0;
    pp[(size_t)(bg * 4 + 1) * N] = acc1;
    pp[(size_t)(bg * 4 + 2) * N] = acc2;
    pp[(size_t)(bg * 4 + 3) * N] = acc3;
}

// A is itself a split-K partial set: A[b,i] = bias[i] + sum_sp2 Ain[sp2][b][i]
template <int K, int ISPL, int N, int RED>
__global__ __launch_bounds__(256) void gemm_partial_red(
        const float* __restrict__ Ain, const float* __restrict__ bias,
        const float* __restrict__ W, float* __restrict__ part) {
    constexpr int IR = K / ISPL;
    __shared__ float Asl[B * IR];
    const int jt  = blockIdx.x;
    const int sp  = blockIdx.y;
    const int i0  = sp * IR;
    const int tid = threadIdx.x;

    for (int e = tid; e < B * IR; e += 256) {
        const int b = e / IR, ii = e % IR;
        float v = bias[i0 + ii];
#pragma unroll
        for (int sp2 = 0; sp2 < RED; ++sp2)
            v += Ain[((size_t)sp2 * B + b) * K + i0 + ii];
        Asl[e] = v;
    }
    __syncthreads();

    const int jl = tid & 63;
    const int bg = tid >> 6;
    const int j  = jt * 64 + jl;
    const float* wp_ = W + (size_t)i0 * N + j;
    const float* a0 = Asl + (bg * 4 + 0) * IR;
    const float* a1 = Asl + (bg * 4 + 1) * IR;
    const float* a2 = Asl + (bg * 4 + 2) * IR;
    const float* a3 = Asl + (bg * 4 + 3) * IR;
    float acc0 = 0.f, acc1 = 0.f, acc2 = 0.f, acc3 = 0.f;
#pragma unroll
    for (int ii = 0; ii < IR; ++ii) {
        const float w = wp_[(size_t)ii * N];
        acc0 += w * a0[ii];
        acc1 += w * a1[ii];
        acc2 += w * a2[ii];
        acc3 += w * a3[ii];
    }
    float* pp = part + ((size_t)sp * B) * N + j;
    pp[(size_t)(bg * 4 + 0) * N] = acc0;
    pp[(size_t)(bg * 4 + 1) * N] = acc1;
    pp[(size_t)(bg * 4 + 2) * N] = acc2;
    pp[(size_t)(bg * 4 + 3) * N] = acc3;
}

// Same but staging applies exact GELU: Asl = gelu(bias + sum parts)
template <int K, int ISPL, int N, int RED>
__global__ __launch_bounds__(256) void gemm_partial_red_gelu(
        const float* __restrict__ Ain, const float* __restrict__ bias,
        const float* __restrict__ W, float* __restrict__ part) {
    constexpr int IR = K / ISPL;
    __shared__ float Asl[B * IR];
    const int jt  = blockIdx.x;
    const int sp  = blockIdx.y;
    const int i0  = sp * IR;
    const int tid = threadIdx.x;

    for (int e = tid; e < B * IR; e += 256) {
        const int b = e / IR, ii = e % IR;
        float v = bias[i0 + ii];
#pragma unroll
        for (int sp2 = 0; sp2 < RED; ++sp2)
            v += Ain[((size_t)sp2 * B + b) * K + i0 + ii];
        Asl[e] = 0.5f * v * (1.0f + erff(v * 0.70710678118654752440f));
    }
    __syncthreads();

    const int jl = tid & 63;
    const int bg = tid >> 6;
    const int j  = jt * 64 + jl;
    const float* wp_ = W + (size_t)i0 * N + j;
    const float* a0 = Asl + (bg * 4 + 0) * IR;
    const float* a1 = Asl + (bg * 4 + 1) * IR;
    const float* a2 = Asl + (bg * 4 + 2) * IR;
    const float* a3 = Asl + (bg * 4 + 3) * IR;
    float acc0 = 0.f, acc1 = 0.f, acc2 = 0.f, acc3 = 0.f;
#pragma unroll 32
    for (int ii = 0; ii < IR; ++ii) {
        const float w = wp_[(size_t)ii * N];
        acc0 += w * a0[ii];
        acc1 += w * a1[ii];
        acc2 += w * a2[ii];
        acc3 += w * a3[ii];
    }
    float* pp = part + ((size_t)sp * B) * N + j;
    pp[(size_t)(bg * 4 + 0) * N] = acc0;
    pp[(size_t)(bg * 4 + 1) * N] = acc1;
    pp[(size_t)(bg * 4 + 2) * N] = acc2;
    pp[(size_t)(bg * 4 + 3) * N] = acc3;
}

// ctx partials with fused 16-way xbar-partial reduction:
//   A[b,i] = sum_s2 xpart[(b*16+s2)*NH*H + jt*H + i]
template <int ISPL>
__global__ __launch_bounds__(256) void gemm_xpart(
        const float* __restrict__ xpart, const float* __restrict__ W,
        float* __restrict__ part) {
    constexpr int IR = H / ISPL;
    __shared__ float Asl[B * IR];
    const int jt  = blockIdx.x;       // head
    const int sp  = blockIdx.y;
    const int i0  = sp * IR;
    const int tid = threadIdx.x;

    for (int e = tid; e < B * IR; e += 256) {
        const int b = e / IR, ii = e % IR;
        float v = 0.f;
#pragma unroll
        for (int s2 = 0; s2 < KSPL; ++s2)
            v += xpart[(((size_t)(b * KSPL + s2)) * NH + jt) * H + i0 + ii];
        Asl[e] = v;
    }
    __syncthreads();

    const int jl = tid & 63;
    const int bg = tid >> 6;
    const int j  = jt * 64 + jl;
    const float* wp_ = W + (size_t)i0 * H + j;
    const float* a0 = Asl + (bg * 4 + 0) * IR;
    const float* a1 = Asl + (bg * 4 + 1) * IR;
    const float* a2 = Asl + (bg * 4 + 2) * IR;
    const float* a3 = Asl + (bg * 4 + 3) * IR;
    float acc0 = 0.f, acc1 = 0.f, acc2 = 0.f, acc3 = 0.f;
#pragma unroll
    for (int ii = 0; ii < IR; ++ii) {
        const float w = wp_[(size_t)ii * H];
        acc0 += w * a0[ii];
        acc1 += w * a1[ii];
        acc2 += w * a2[ii];
        acc3 += w * a3[ii];
    }
    float* pp = part + ((size_t)sp * B) * H + j;
    pp[(size_t)(bg * 4 + 0) * H] = acc0;
    pp[(size_t)(bg * 4 + 1) * H] = acc1;
    pp[(size_t)(bg * 4 + 2) * H] = acc2;
    pp[(size_t)(bg * 4 + 3) * H] = acc3;
}

// u[b,h,i] = sum_d wk[i, h*64+d] * (q0 reduced); constk[b,h] = bk_h . q0_h
__global__ __launch_bounds__(256) void u_kernel(
        const float* __restrict__ q0_part, const float* __restrict__ bq,
        const float* __restrict__ wk, const float* __restrict__ bk,
        float* __restrict__ u, float* __restrict__ constk) {
    const int b = blockIdx.x / NH, h = blockIdx.x % NH;
    __shared__ float qh[DH];
    const int tid = threadIdx.x;
    if (tid < DH) {
        float v = bq[h * DH + tid];
#pragma unroll
        for (int sp = 0; sp < 24; ++sp)
            v += q0_part[((size_t)sp * B + b) * H + h * DH + tid];
        qh[tid] = v;
    }
    __syncthreads();
    if (tid < DH) {
        float v = bk[h * DH + tid] * qh[tid];
        v = waveReduceSum(v);
        if (tid == 0) constk[b * NH + h] = v;
    }
    const int jj = tid & 3, iq = tid >> 2;
    const float4* qv = (const float4*)qh;
    float4 q4[4];
#pragma unroll
    for (int c = 0; c < 4; ++c) q4[c] = qv[jj * 4 + c];
#pragma unroll 4
    for (int ir = 0; ir < 12; ++ir) {
        const int i = ir * 64 + iq;
        const float4* wr = (const float4*)(wk + (size_t)i * H + h * DH);
        float s = 0.f;
#pragma unroll
        for (int c = 0; c < 4; ++c) {
            const float4 w = wr[jj * 4 + c];
            s += w.x * q4[c].x + w.y * q4[c].y + w.z * q4[c].z + w.w * q4[c].w;
        }
        s += __shfl_xor(s, 1);
        s += __shfl_xor(s, 2);
        if (jj == 0) u[((size_t)(b * NH + h)) * H + i] = s;
    }
}

// e_t[b][k][h] = exp( x[b,k]·u[b,h]/8 + constk + mask )   (no max: |score|<~5)
// psum[b][kt][h] = sum of e over this block's 32 k's
// grid (B, S/32), block 256
__global__ __launch_bounds__(256, 2) void score_kernel(
        const float* __restrict__ x, const float* __restrict__ u,
        const float* __restrict__ constk, const float* __restrict__ mask,
        float* __restrict__ e_t, float* __restrict__ psum) {
    const int b  = blockIdx.x;
    const int kt = blockIdx.y;
    __shared__ __align__(16) float ul[NH * H];
    __shared__ float ck[NH];
    __shared__ float wsum[4][NH];
    const int tid = threadIdx.x;
    {
        const float4* ug = (const float4*)(u + (size_t)b * NH * H);
        float4* ul4 = (float4*)ul;
        for (int e = tid; e < NH * H / 4; e += 256) ul4[e] = ug[e];
        if (tid < NH) ck[tid] = constk[b * NH + tid];
    }
    __syncthreads();

    const int jj = tid & 15, kk = tid >> 4;
    const int k0 = kt * 32 + kk * 2;
    float4 xv0[12], xv1[12];
    {
        const float4* xr0 = (const float4*)(x + ((size_t)b * S + k0) * H);
        const float4* xr1 = (const float4*)(x + ((size_t)b * S + k0 + 1) * H);
#pragma unroll
        for (int t = 0; t < 12; ++t) { xv0[t] = xr0[jj + 16 * t]; xv1[t] = xr1[jj + 16 * t]; }
    }
    const float4* ul4 = (const float4*)ul;
    float acc0[NH], acc1[NH];
#pragma unroll
    for (int h = 0; h < NH; ++h) {
        float a0 = 0.f, a1 = 0.f;
#pragma unroll
        for (int t = 0; t < 12; ++t) {
            const float4 uv = ul4[h * 192 + jj + 16 * t];
            a0 += xv0[t].x * uv.x + xv0[t].y * uv.y + xv0[t].z * uv.z + xv0[t].w * uv.w;
            a1 += xv1[t].x * uv.x + xv1[t].y * uv.y + xv1[t].z * uv.z + xv1[t].w * uv.w;
        }
        acc0[h] = a0; acc1[h] = a1;
    }
#pragma unroll
    for (int h = 0; h < NH; ++h) {
#pragma unroll
        for (int d = 1; d < 16; d <<= 1) {
            acc0[h] += __shfl_xor(acc0[h], d);
            acc1[h] += __shfl_xor(acc1[h], d);
        }
    }
    // exponentials (all 16 jj lanes hold identical sums)
    const float mk0 = mask[b * S + k0];
    const float mk1 = mask[b * S + k0 + 1];
    float e0[NH], e1[NH], ps[NH];
#pragma unroll
    for (int h = 0; h < NH; ++h) {
        e0[h] = expf(acc0[h] * 0.125f + ck[h] + mk0);
        e1[h] = expf(acc1[h] * 0.125f + ck[h] + mk1);
        ps[h] = e0[h] + e1[h];
    }
    if (jj == 0) {
        float4* er0 = (float4*)(e_t + ((size_t)(b * S + k0)) * NH);
        float4* er1 = (float4*)(e_t + ((size_t)(b * S + k0 + 1)) * NH);
        er0[0] = make_float4(e0[0], e0[1], e0[2], e0[3]);
        er0[1] = make_float4(e0[4], e0[5], e0[6], e0[7]);
        er0[2] = make_float4(e0[8], e0[9], e0[10], e0[11]);
        er1[0] = make_float4(e1[0], e1[1], e1[2], e1[3]);
        er1[1] = make_float4(e1[4], e1[5], e1[6], e1[7]);
        er1[2] = make_float4(e1[8], e1[9], e1[10], e1[11]);
    }
    // cross-kk reduce: within wave, kk groups are lanes {0,16,32,48}+jj
#pragma unroll
    for (int h = 0; h < NH; ++h) {
        ps[h] += __shfl_xor(ps[h], 16);
        ps[h] += __shfl_xor(ps[h], 32);
    }
    const int wid = tid >> 6;
    if ((tid & 63) == 0) {
#pragma unroll
        for (int h = 0; h < NH; ++h) wsum[wid][h] = ps[h];
    }
    __syncthreads();
    if (tid < NH)
        psum[((size_t)(b * 32 + kt)) * NH + tid] =
            wsum[0][tid] + wsum[1][tid] + wsum[2][tid] + wsum[3][tid];
}

// xpart[b,sp,h,j] = (1/rowsum) * sum_{k in split} e_t[b,k,h] * x[b,k,j]
// grid (B, KSPL), block 768
__global__ __launch_bounds__(768) void xbar_partial(
        const float* __restrict__ x, const float* __restrict__ e_t,
        const float* __restrict__ psum, float* __restrict__ xpart) {
    constexpr int KR = S / KSPL;   // 64
    const int b = blockIdx.x, sp = blockIdx.y;
    const int tid = threadIdx.x;
    __shared__ float rinv[NH];
    if (tid < NH) {
        float s = 0.f;
#pragma unroll
        for (int kt = 0; kt < 32; ++kt) s += psum[((size_t)(b * 32 + kt)) * NH + tid];
        rinv[tid] = 1.0f / s;
    }
    float acc[NH];
#pragma unroll
    for (int h = 0; h < NH; ++h) acc[h] = 0.f;
    const float* xr = x + ((size_t)b * S + sp * KR) * H + tid;
    const float* er = e_t + ((size_t)b * S + sp * KR) * NH;
#pragma unroll 8
    for (int kk = 0; kk < KR; ++kk) {
        const float xv = xr[(size_t)kk * H];
#pragma unroll
        for (int h = 0; h < NH; ++h) acc[h] += er[kk * NH + h] * xv;
    }
    __syncthreads();
    float* op = xpart + ((size_t)(b * KSPL + sp)) * NH * H + tid;
#pragma unroll
    for (int h = 0; h < NH; ++h) op[(size_t)h * H] = acc[h] * rinv[h];
}

// out[b,:] = LayerNorm( sum_sp part + bias + resid ) * g + beta
template <int ISPL>
__global__ __launch_bounds__(768) void ln_kernel(
        const float* __restrict__ part, const float* __restrict__ bias,
        const float* __restrict__ resid, int residStride,
        const float* __restrict__ g, const float* __restrict__ bet,
        float* __restrict__ out) {
    __shared__ float red[12];
    const int b = blockIdx.x, j = threadIdx.x;
    float v = bias[j] + resid[(size_t)b * residStride + j];
#pragma unroll
    for (int sp = 0; sp < ISPL; ++sp) v += part[((size_t)sp * B + b) * H + j];
    const float mu = blockReduceSum768(v, red) * (1.0f / H);
    const float d  = v - mu;
    const float var = blockReduceSum768(d * d, red) * (1.0f / H);
    out[(size_t)b * H + j] = d * rsqrtf(var + EPS) * g[j] + bet[j];
}

// pooled = tanh(sum_sp part + bp); cls[b] = pooled . wm + bm
template <int ISPL>
__global__ __launch_bounds__(768) void cls_kernel(
        const float* __restrict__ part, const float* __restrict__ bp,
        const float* __restrict__ wm, const float* __restrict__ bm,
        float* __restrict__ out) {
    __shared__ float red[12];
    const int b = blockIdx.x, j = threadIdx.x;
    float v = bp[j];
#pragma unroll
    for (int sp = 0; sp < ISPL; ++sp) v += part[((size_t)sp * B + b) * H + j];
    v = tanhf(v);
    const float s = blockReduceSum768(v * wm[j], red);
    if (j == 0) out[b] = s + bm[0];
}

} // namespace

extern "C" void kernel_launch(void* const* d_in, const int* in_sizes, int n_in,
                              void* d_out, int out_size, void* d_ws, size_t ws_size,
                              hipStream_t stream) {
    const float* x    = (const float*)d_in[0];
    const float* mask = (const float*)d_in[1];
    const float* wq   = (const float*)d_in[2];
    const float* bq   = (const float*)d_in[3];
    const float* wk   = (const float*)d_in[4];
    const float* bk   = (const float*)d_in[5];
    const float* wv   = (const float*)d_in[6];
    const float* bv   = (const float*)d_in[7];
    const float* wo   = (const float*)d_in[8];
    const float* bo   = (const float*)d_in[9];
    const float* ln1g = (const float*)d_in[10];
    const float* ln1b = (const float*)d_in[11];
    const float* w1   = (const float*)d_in[12];
    const float* b1   = (const float*)d_in[13];
    const float* w2   = (const float*)d_in[14];
    const float* b2   = (const float*)d_in[15];
    const float* ln2g = (const float*)d_in[16];
    const float* ln2b = (const float*)d_in[17];
    const float* wp   = (const float*)d_in[18];
    const float* bp   = (const float*)d_in[19];
    const float* wm   = (const float*)d_in[20];
    const float* bm   = (const float*)d_in[21];
    float* out = (float*)d_out;

    // -------- workspace (lifetime-overlapped arena; ~13.3 MB) --------
    float* ws = (float*)d_ws;
    size_t o = 0;
    float* u        = ws + o; o += (size_t)B * NH * H;      // 147456
    float* constk   = ws + o; o += 256;
    float* e_t      = ws + o; o += (size_t)B * S * NH;      // 196608
    float* psum     = ws + o; o += (size_t)B * 32 * NH;     // 6144
    float* attn_out = ws + o; o += (size_t)B * H;
    float* hidden   = ws + o; o += (size_t)B * H;
    float* arena    = ws + o;
    // arena aliases (sequential lifetimes):
    float* q0_part   = arena;                                  // 24*B*H, dies after u
    float* xpart     = arena;                                  // KSPL*B*NH*H = 2359296
    float* ctx_part  = arena + (size_t)KSPL * B * NH * H;      // 24*B*H (reads xpart)
    float* wo_part   = ctx_part + (size_t)24 * B * H;          // 24*B*H (reads ctx_part)
    float* ffn1_part = arena;                                  // 24*B*FF = 1179648 (xpart dead)
    float* ffn2_part = arena + (size_t)24 * B * FF;            // 48*B*H (reads ffn1_part)
    float* pool_part = arena;                                  // 24*B*H
    (void)ws_size; (void)in_sizes; (void)n_in; (void)out_size;

    // 1) q0 partials = x[:,0,:] @ wq
    gemm_partial<H, 24, H><<<dim3(12, 24), 256, 0, stream>>>(x, S * H, 0, wq, q0_part);

    // 2) u[b,h,:] = wk_head @ q0_head (fused q0 reduce + bq); constk = bk_h . q0_h
    u_kernel<<<B * NH, 256, 0, stream>>>(q0_part, bq, wk, bk, u, constk);

    // 3) e = exp(scores) + row-sum partials  (reads x once; softmax fused)
    score_kernel<<<dim3(B, S / 32), 256, 0, stream>>>(x, u, constk, mask, e_t, psum);

    // 4) xbar partials, normalized inline  (reads x once more, L3-warm)
    xbar_partial<<<dim3(B, KSPL), 768, 0, stream>>>(x, e_t, psum, xpart);

    // 5) ctx partials: per-head xbar slice @ wv (fused 16-way xpart reduce)
    gemm_xpart<24><<<dim3(12, 24), 256, 0, stream>>>(xpart, wv, ctx_part);

    // 6) wo GEMM (fused ctx reduce + bv); LN1 with residual x[:,0,:]
    gemm_partial_red<H, 24, H, 24><<<dim3(12, 24), 256, 0, stream>>>(ctx_part, bv, wo, wo_part);
    ln_kernel<24><<<B, 768, 0, stream>>>(wo_part, bo, x, S * H, ln1g, ln1b, attn_out);

    // 7) FFN (gelu fused into ffn2 staging)
    gemm_partial<H, 24, FF><<<dim3(48, 24), 256, 0, stream>>>(attn_out, H, 0, w1, ffn1_part);
    gemm_partial_red_gelu<FF, 48, H, 24><<<dim3(12, 48), 256, 0, stream>>>(ffn1_part, b1, w2, ffn2_part);
    ln_kernel<48><<<B, 768, 0, stream>>>(ffn2_part, b2, attn_out, H, ln2g, ln2b, hidden);

    // 8) pooler + classifier
    gemm_partial<H, 24, H><<<dim3(12, 24), 256, 0, stream>>>(hidden, H, 0, wp, pool_part);
    cls_kernel<24><<<B, 768, 0, stream>>>(pool_part, bp, wm, bm, out);
}